// Round 13
// baseline (63.034 us; speedup 1.0000x reference)
//
#include <hip/hip_runtime.h>
#include <hip/hip_bf16.h>

#define NEG (-1e6f)

static constexpr int B = 32, Q = 64, K = 512, H = 64, V = 64;
static constexpr float C2LE = 2.8853900817779268f;   // 2*log2(e)
static constexpr float L2E  = 1.4426950408889634f;   // log2(e)

typedef __attribute__((ext_vector_type(8))) short bf16x8;
typedef __attribute__((ext_vector_type(4))) float f32x4;

__device__ __forceinline__ float fexp2(float x) { return __builtin_amdgcn_exp2f(x); }
__device__ __forceinline__ float frcp(float x)  { return __builtin_amdgcn_rcpf(x); }

// HW packed RNE f32x2 -> bf16x2 (v_cvt_pk_bf16_f32): 1 instr per 2 elements.
__device__ __forceinline__ unsigned pk(float a, float b) {
  __hip_bfloat162 h = __float22bfloat162_rn(make_float2(a, b));
  return *reinterpret_cast<unsigned*>(&h);
}
union bfrag { unsigned u[4]; bf16x8 v; };

// ---- ONE plain kernel, zero cross-block deps. Block = (b, 4 queries),
// 512 threads = 8 waves, grid 512 = 8 XCDs x 64 slots, 2 blocks/CU (64KB LDS).
// b scrambled bijectively so co-resident slot pairs (s, s+32) serve different
// batches (different vlens -> balanced CU, fixes r8's 13% occupancy).
// Each block q-projects its own 4 queries (waves 0..3, MFMA) to a private ws
// slice, and k-projects its batch's live keys DIRECTLY into LDS (all 8 waves,
// MFMA, vlen-skipped stripes). Redundancy (16 blocks/b) is cheap now: HW
// v_cvt_pk conversions (r8 died of ~10-op software f2bf, not of fusion).
// Math: wv_h*tanh(q+k) = wv_h + A_h*rcp(R_h+E_h), A=-2wv_h e^{-2q}, R=e^{-2q},
// E=e^{2k}; const sum(wv) dropped (softmax shift-inv); clamp +-15 pre-exp.
// MFMA 16x16x32 bf16 (m89/m91): A: row=l&15,k=(l>>4)*8+j; B: col=l&15 same k;
// C/D: col=l&15, row=(l>>4)*4+reg; swapped operands transpose D (key tiles
// come out h-major). LDS: ekl 64KB; p (8KB) + part (8KB) overlay dead ekl.
__global__ __launch_bounds__(512, 4) void fused_kernel(
    const float* __restrict__ queries, const float* __restrict__ keys,
    const float* __restrict__ values, const int* __restrict__ vlens,
    const float* __restrict__ Wq, const float* __restrict__ Wk,
    const float* __restrict__ wv,
    float* __restrict__ qar_ws, float* __restrict__ out)
{
  __shared__ unsigned ekl[32 * 512];   // 64KB E packed; p/part overlay later
  __shared__ float red[4][2][2];       // [query][half][max,sum]

  const int tid = threadIdx.x, lane = tid & 63;
  const int wave = __builtin_amdgcn_readfirstlane(tid >> 6);
  const int xcd = blockIdx.x & 7, slot = blockIdx.x >> 3;
  const int b  = xcd * 4 + ((slot + (slot >> 5)) & 3);   // bijective scramble
  const int qg = slot >> 2;                              // qg in [0,16)
  const int vlen = vlens[b];
  const int r = lane & 15, g = lane >> 4;

  // ---- phase A0: q-projection (waves 0..3): stripe (qg>>2)*16, h-tile=wave
  if (wave < 4) {
    const float* px = queries + ((size_t)b * Q + (qg >> 2) * 16 + r) * H;
    const int hcol = wave * 16 + r;
    f32x4 acc = {0.f, 0.f, 0.f, 0.f};
    #pragma unroll
    for (int kb = 0; kb < 2; ++kb) {
      const float4 x0 = *(const float4*)(px + kb * 32 + g * 8);
      const float4 x1 = *(const float4*)(px + kb * 32 + g * 8 + 4);
      bfrag a, w;
      a.u[0] = pk(x0.x, x0.y); a.u[1] = pk(x0.z, x0.w);
      a.u[2] = pk(x1.x, x1.y); a.u[3] = pk(x1.z, x1.w);
      #pragma unroll
      for (int jj = 0; jj < 4; ++jj)
        w.u[jj] = pk(Wq[(kb * 32 + g * 8 + 2*jj    ) * H + hcol],
                     Wq[(kb * 32 + g * 8 + 2*jj + 1) * H + hcol]);
      acc = __builtin_amdgcn_mfma_f32_16x16x32_bf16(a.v, w.v, acc, 0, 0, 0);
    }
    if (g == (qg & 3)) {               // this lane's 4 rows = the block's queries
      const float wvv = wv[hcol];
      float* dst = qar_ws + (size_t)(b * 16 + qg) * 512
                          + (hcol >> 1) * 16 + (hcol & 1) * 2;
      #pragma unroll
      for (int rr = 0; rr < 4; ++rr) { // qi = rr
        const float s = fminf(15.f, fmaxf(-15.f, acc[rr])) * C2LE;
        const float rq = fexp2(-s);
        *(float2*)(dst + rr * 4) = make_float2(-2.f * wvv * rq, rq);
      }
    }
  }

  // ---- phase A1: k-projection -> LDS (all 8 waves), vlen-skipped stripes
  {
    const int t = wave & 3;            // h-tile of this wave
    bfrag wk[2];
    #pragma unroll
    for (int kb = 0; kb < 2; ++kb)
      #pragma unroll
      for (int jj = 0; jj < 4; ++jj)
        wk[kb].u[jj] = pk(Wk[(kb * 32 + g * 8 + 2*jj    ) * H + t * 16 + r],
                          Wk[(kb * 32 + g * 8 + 2*jj + 1) * H + t * 16 + r]);

    for (int s = (wave >> 2); s * 16 < vlen; s += 2) {
      const float* px = keys + ((size_t)b * K + s * 16 + r) * H;
      f32x4 acc = {0.f, 0.f, 0.f, 0.f};
      #pragma unroll
      for (int kb = 0; kb < 2; ++kb) {
        const float4 x0 = *(const float4*)(px + kb * 32 + g * 8);
        const float4 x1 = *(const float4*)(px + kb * 32 + g * 8 + 4);
        bfrag a;
        a.u[0] = pk(x0.x, x0.y); a.u[1] = pk(x0.z, x0.w);
        a.u[2] = pk(x1.x, x1.y); a.u[3] = pk(x1.z, x1.w);
        acc = __builtin_amdgcn_mfma_f32_16x16x32_bf16(wk[kb].v, a.v, acc, 0, 0, 0);
      }
      // D transposed: col(=k)=r, row(=h)=t*16+g*4+rr; pack h-pairs as bf16x2
      float E[4];
      #pragma unroll
      for (int rr = 0; rr < 4; ++rr)
        E[rr] = fexp2(fminf(15.f, fmaxf(-15.f, acc[rr])) * C2LE);
      const int k = s * 16 + r;
      const int hp = t * 8 + g * 2;
      ekl[ hp      * 512 + k] = pk(E[0], E[1]);
      ekl[(hp + 1) * 512 + k] = pk(E[2], E[3]);
    }
  }
  __syncthreads();                     // ekl complete; qar_ws stores drained

  // ---- phase 1: scores, thread = key tid; waves fully past vlen skip
  float a0 = 0.f, a1 = 0.f, a2 = 0.f, a3 = 0.f;
  if (wave * 64 < vlen) {
    const float* ar = qar_ws +
        (size_t)__builtin_amdgcn_readfirstlane((b * 16 + qg) * 512);
    #pragma unroll
    for (int hp = 0; hp < 32; ++hp) {
      const unsigned u = ekl[hp * 512 + tid];    // ds_read_b32, conflict-free
      const float E0 = __uint_as_float(u << 16);
      const float E1 = __uint_as_float(u & 0xffff0000u);
      const float* s = ar + hp * 16;             // uniform -> s_load
      a0 = fmaf(s[ 0], frcp(s[ 1] + E0), a0);
      a0 = fmaf(s[ 2], frcp(s[ 3] + E1), a0);
      a1 = fmaf(s[ 4], frcp(s[ 5] + E0), a1);
      a1 = fmaf(s[ 6], frcp(s[ 7] + E1), a1);
      a2 = fmaf(s[ 8], frcp(s[ 9] + E0), a2);
      a2 = fmaf(s[10], frcp(s[11] + E1), a2);
      a3 = fmaf(s[12], frcp(s[13] + E0), a3);
      a3 = fmaf(s[14], frcp(s[15] + E1), a3);
    }
  }
  __syncthreads();                     // all ekl reads done -> overlay safe
  float* p    = (float*)ekl;           // p[qi*512 + k]       (8KB)
  float* part = (float*)ekl + 2048;    // part[(w*4+qi)*64+v] (8KB)
  if (wave * 64 < vlen) {
    p[0 * 512 + tid] = a0; p[1 * 512 + tid] = a1;
    p[2 * 512 + tid] = a2; p[3 * 512 + tid] = a3;
  }
  __syncthreads();

  // ---- phase 2: masked softmax; wave = (query, half of K). 8 waves busy.
  const int qi = wave & 3, half = wave >> 2;
  const int kb2 = half * 256 + lane * 4;
  {
    float s[4];
    *(float4*)s = *(const float4*)&p[qi * 512 + kb2]; // garbage past vlen: masked
    float m = NEG;
    #pragma unroll
    for (int j = 0; j < 4; ++j) {
      s[j] = (kb2 + j < vlen) ? s[j] : NEG;
      m = fmaxf(m, s[j]);
    }
    #pragma unroll
    for (int off = 32; off; off >>= 1) m = fmaxf(m, __shfl_xor(m, off, 64));
    if (lane == 0) red[qi][half][0] = m;
    __syncthreads();
    m = fmaxf(red[qi][0][0], red[qi][1][0]);
    float sum = 0.f;
    #pragma unroll
    for (int j = 0; j < 4; ++j) { s[j] = fexp2((s[j] - m) * L2E); sum += s[j]; }
    *(float4*)&p[qi * 512 + kb2] = *(float4*)s;       // zeros beyond vlen
    #pragma unroll
    for (int off = 32; off; off >>= 1) sum += __shfl_xor(sum, off, 64);
    if (lane == 0) red[qi][half][1] = sum;
    __syncthreads();
  }

  // ---- phase 3: PV, vlen-chunked: all 8 waves split [0, vlen). lane = v.
  {
    const int chunk = ((vlen + 31) >> 5) << 2;   // ceil(vlen/8) -> mult of 4
    const int kb = wave * chunk;
    const float* vb = values + ((size_t)b * K + kb) * V + lane;
    float c0 = 0.f, c1 = 0.f, c2 = 0.f, c3 = 0.f;
    #pragma unroll 4
    for (int k4 = 0; k4 < chunk; k4 += 4) {
      const float4 p0 = *(const float4*)&p[0 * 512 + kb + k4];  // uniform bcast
      const float4 p1 = *(const float4*)&p[1 * 512 + kb + k4];
      const float4 p2 = *(const float4*)&p[2 * 512 + kb + k4];
      const float4 p3 = *(const float4*)&p[3 * 512 + kb + k4];
      const float v0 = vb[(size_t)(k4 + 0) * V];
      const float v1 = vb[(size_t)(k4 + 1) * V];
      const float v2 = vb[(size_t)(k4 + 2) * V];
      const float v3 = vb[(size_t)(k4 + 3) * V];
      c0 = fmaf(p0.x,v0, fmaf(p0.y,v1, fmaf(p0.z,v2, fmaf(p0.w,v3, c0))));
      c1 = fmaf(p1.x,v0, fmaf(p1.y,v1, fmaf(p1.z,v2, fmaf(p1.w,v3, c1))));
      c2 = fmaf(p2.x,v0, fmaf(p2.y,v1, fmaf(p2.z,v2, fmaf(p2.w,v3, c2))));
      c3 = fmaf(p3.x,v0, fmaf(p3.y,v1, fmaf(p3.z,v2, fmaf(p3.w,v3, c3))));
    }
    part[(wave*4+0)*64+lane] = c0; part[(wave*4+1)*64+lane] = c1;
    part[(wave*4+2)*64+lane] = c2; part[(wave*4+3)*64+lane] = c3;
  }
  __syncthreads();

  // ---- phase 4: cross-wave reduce + normalize + write (waves 0..3)
  if (wave < 4) {
    const float inv = frcp(red[wave][0][1] + red[wave][1][1]);
    float o = 0.f;
    #pragma unroll
    for (int w = 0; w < 8; ++w) o += part[(w*4+wave)*64 + lane];
    out[((size_t)b * Q + qg * 4 + wave) * V + lane] = o * inv;
  }
}

extern "C" void kernel_launch(void* const* d_in, const int* in_sizes, int n_in,
                              void* d_out, int out_size, void* d_ws, size_t ws_size,
                              hipStream_t stream) {
  const float* queries = (const float*)d_in[0];
  const float* keys    = (const float*)d_in[1];
  const float* values  = (const float*)d_in[2];
  const int*   vlens   = (const int*)d_in[3];
  const float* Wq      = (const float*)d_in[4];
  const float* Wk      = (const float*)d_in[5];
  const float* wv      = (const float*)d_in[6];
  float* out = (float*)d_out;
  float* qar_ws = (float*)d_ws;                  // 512 slices x 512 dwords = 1MB

  fused_kernel<<<512, 512, 0, stream>>>(queries, keys, values, vlens,
                                        Wq, Wk, wv, qar_ws, out);
}

// Round 14
// 23.594 us; speedup vs baseline: 2.6716x; 2.6716x over previous
//
#include <hip/hip_runtime.h>
#include <hip/hip_bf16.h>

#define NEG (-1e6f)

static constexpr int B = 32, Q = 64, K = 512, H = 64, V = 64;
static constexpr float C2LE = 2.8853900817779268f;   // 2*log2(e)
static constexpr float L2E  = 1.4426950408889634f;   // log2(e)

typedef __attribute__((ext_vector_type(8))) short bf16x8;
typedef __attribute__((ext_vector_type(4))) float f32x4;

__device__ __forceinline__ float fexp2(float x) { return __builtin_amdgcn_exp2f(x); }
__device__ __forceinline__ float frcp(float x)  { return __builtin_amdgcn_rcpf(x); }

// HW packed RNE f32x2 -> bf16x2 (v_cvt_pk_bf16_f32): 1 instr per 2 elements.
__device__ __forceinline__ unsigned pk(float a, float b) {
  __hip_bfloat162 h = __float22bfloat162_rn(make_float2(a, b));
  return *reinterpret_cast<unsigned*>(&h);
}
union bfrag { unsigned u[4]; bf16x8 v; };

// ---- micro-block projections: 1152 blocks x 64 threads (1 wave, 1 stripe),
// no LDS, no barrier; 4.5 waves/CU -> balanced, tiny critical path.
// Unit mapping (XCD-affine, consumer XCD = producer XCD):
//   bid -> xcd = bid&7, u = bid>>3 in [0,144)
//   u 0..15:   q-stripe,  b = xcd*4 + (u>>2),      str = u&3    (16 rows)
//   u 16..143: k-stripe,  b = xcd*4 + ((u-16)&3),  str = (u-16)>>2
//              exits immediately when str*16 >= vlen[b].
// W fragments are read straight from global (L1-resident 16KB, r13-verified
// pattern). Outputs (r9/r11 layouts):
//   qAR2[(((b*16+qg)*32+hp)*16) + qi*4 + (h&1)*2 + {A,R}]
//     A = -2*wv_h*e^{-2q}, R = e^{-2q}
//   Ekp[b][hp][k] = {bf16(e^{2k_h0}), bf16(e^{2k_h1})} packed dword
// Math: wv_h*tanh(q+k) = wv_h + A*rcp(R+E); const sum(wv) dropped (softmax
// shift-inv); clamp +-15 pre-exp. MFMA 16x16x32 bf16 (m89/m91 layout);
// swapped operands transpose D so key tiles come out h-major.
__global__ __launch_bounds__(64) void proj_kernel(
    const float* __restrict__ queries, const float* __restrict__ keys,
    const float* __restrict__ Wq, const float* __restrict__ Wk,
    const float* __restrict__ wv, const int* __restrict__ vlens,
    float* __restrict__ qAR2, unsigned* __restrict__ Ekp)
{
  const int xcd = blockIdx.x & 7, u = blockIdx.x >> 3;
  const bool isQ = u < 16;
  const int b   = xcd * 4 + (isQ ? (u >> 2) : ((u - 16) & 3));
  const int str = isQ ? (u & 3) : ((u - 16) >> 2);
  if (!isQ && str * 16 >= vlens[b]) return;      // dead k-stripe

  const int lane = threadIdx.x & 63;
  const int r = lane & 15, g = lane >> 4;
  const float* W = isQ ? Wq : Wk;
  const float* xbase = isQ ? (queries + ((size_t)b * Q + str * 16) * H)
                           : (keys    + ((size_t)b * K + str * 16) * H);

  bf16x8 afr[2];
  #pragma unroll
  for (int kb = 0; kb < 2; ++kb) {               // X frag: 8 contiguous k/lane
    const float* px = xbase + (size_t)r * H + kb * 32 + g * 8;
    const float4 x0 = *(const float4*)px;
    const float4 x1 = *(const float4*)(px + 4);
    bfrag a;
    a.u[0] = pk(x0.x, x0.y); a.u[1] = pk(x0.z, x0.w);
    a.u[2] = pk(x1.x, x1.y); a.u[3] = pk(x1.z, x1.w);
    afr[kb] = a.v;
  }

  #pragma unroll
  for (int t = 0; t < 4; ++t) {                  // 4 h-tiles of 16
    const int hcol = t * 16 + r;
    f32x4 acc = {0.f, 0.f, 0.f, 0.f};
    #pragma unroll
    for (int kb = 0; kb < 2; ++kb) {
      bfrag w;
      #pragma unroll
      for (int jj = 0; jj < 4; ++jj)
        w.u[jj] = pk(W[(kb * 32 + g * 8 + 2*jj    ) * H + hcol],
                     W[(kb * 32 + g * 8 + 2*jj + 1) * H + hcol]);
      acc = isQ ? __builtin_amdgcn_mfma_f32_16x16x32_bf16(afr[kb], w.v, acc, 0, 0, 0)
                : __builtin_amdgcn_mfma_f32_16x16x32_bf16(w.v, afr[kb], acc, 0, 0, 0);
    }
    if (isQ) {
      // D: col(=h)=r, row(=q-row)=g*4+reg
      const float wvv = wv[hcol];
      #pragma unroll
      for (int rr = 0; rr < 4; ++rr) {
        const int qq = str * 16 + g * 4 + rr;
        const float s = fminf(15.f, fmaxf(-15.f, acc[rr])) * C2LE;
        const float rq = fexp2(-s);
        const size_t off = (((size_t)(b * 16 + (qq >> 2)) * 32 + (hcol >> 1)) * 16)
                           + (qq & 3) * 4 + (hcol & 1) * 2;
        *(float2*)(qAR2 + off) = make_float2(-2.f * wvv * rq, rq);
      }
    } else {
      // D transposed: col(=k)=r, row(=h)=t*16+g*4+reg; pack h-pairs
      const int k = str * 16 + r;
      float E[4];
      #pragma unroll
      for (int rr = 0; rr < 4; ++rr)
        E[rr] = fexp2(fminf(15.f, fmaxf(-15.f, acc[rr])) * C2LE);
      const int hp = t * 8 + g * 2;
      Ekp[((size_t)b * 32 + hp    ) * 512 + k] = pk(E[0], E[1]);
      Ekp[((size_t)b * 32 + hp + 1) * 512 + k] = pk(E[2], E[3]);
    }
  }
}

// ---- fused attention (r11 champion, verbatim): grid 512 = 8 XCDs x 64
// slots; block=(b, 4 queries), 512 threads = 8 waves, 2 blocks/CU (64KB LDS).
// b scrambled so co-resident slot pairs differ in vlen; Ekp[b] staged to LDS
// via register staging; score add+rcp+fma with s_load A/R; p/part overlay
// dead ekl; chunked PV.
__global__ __launch_bounds__(512) void attn_kernel(
    const float* __restrict__ qAR2, const unsigned* __restrict__ Ekp,
    const float* __restrict__ values, const int* __restrict__ vlens,
    float* __restrict__ out)
{
  __shared__ unsigned ekl[32 * 512];   // 64KB staged E; p/part overlay
  __shared__ float red[4][2][2];       // [query][half][max,sum]

  const int xcd = blockIdx.x & 7, slot = blockIdx.x >> 3;
  const int b  = xcd * 4 + ((slot + (slot >> 5)) & 3);   // bijective scramble
  const int qg = slot >> 2;                              // qg in [0,16)
  const int vlen = vlens[b];
  const int tid = threadIdx.x, lane = tid & 63;
  const int wave = __builtin_amdgcn_readfirstlane(tid >> 6);

  // ---- stage Ekp[b] -> LDS: 64 chunks x 1KB; skip chunks fully past vlen
  {
    const unsigned* src = Ekp + (size_t)b * 32 * 512;
    #pragma unroll
    for (int i = 0; i < 8; ++i) {
      const int c = i * 8 + wave;
      if ((c & 1) * 256 < vlen) {
        const uint4 v = *(const uint4*)(src + c * 256 + lane * 4);
        *(uint4*)&ekl[c * 256 + lane * 4] = v;   // ds_write_b128, linear
      }
    }
  }
  __syncthreads();

  // ---- phase 1: scores, thread = key tid; waves fully past vlen skip
  float a0 = 0.f, a1 = 0.f, a2 = 0.f, a3 = 0.f;
  if (wave * 64 < vlen) {
    const float* ar = qAR2 +
        (size_t)__builtin_amdgcn_readfirstlane((b * 16 + qg) * 512);
    #pragma unroll
    for (int hp = 0; hp < 32; ++hp) {
      const unsigned u = ekl[hp * 512 + tid];    // ds_read_b32, conflict-free
      const float E0 = __uint_as_float(u << 16);
      const float E1 = __uint_as_float(u & 0xffff0000u);
      const float* s = ar + hp * 16;             // uniform -> s_load
      a0 = fmaf(s[ 0], frcp(s[ 1] + E0), a0);
      a0 = fmaf(s[ 2], frcp(s[ 3] + E1), a0);
      a1 = fmaf(s[ 4], frcp(s[ 5] + E0), a1);
      a1 = fmaf(s[ 6], frcp(s[ 7] + E1), a1);
      a2 = fmaf(s[ 8], frcp(s[ 9] + E0), a2);
      a2 = fmaf(s[10], frcp(s[11] + E1), a2);
      a3 = fmaf(s[12], frcp(s[13] + E0), a3);
      a3 = fmaf(s[14], frcp(s[15] + E1), a3);
    }
  }
  __syncthreads();                      // all ekl reads done -> overlay safe
  float* p    = (float*)ekl;            // p[qi*512 + k]       (8KB)
  float* part = (float*)ekl + 2048;     // part[(w*4+qi)*64+v] (8KB)
  if (wave * 64 < vlen) {
    p[0 * 512 + tid] = a0; p[1 * 512 + tid] = a1;
    p[2 * 512 + tid] = a2; p[3 * 512 + tid] = a3;
  }
  __syncthreads();

  // ---- phase 2: masked softmax; wave = (query, half of K). 8 waves busy.
  const int qi = wave & 3, half = wave >> 2;
  const int kb2 = half * 256 + lane * 4;
  {
    float s[4];
    *(float4*)s = *(const float4*)&p[qi * 512 + kb2];  // garbage past vlen: masked
    float m = NEG;
    #pragma unroll
    for (int j = 0; j < 4; ++j) {
      s[j] = (kb2 + j < vlen) ? s[j] : NEG;
      m = fmaxf(m, s[j]);
    }
    #pragma unroll
    for (int off = 32; off; off >>= 1) m = fmaxf(m, __shfl_xor(m, off, 64));
    if (lane == 0) red[qi][half][0] = m;
    __syncthreads();
    m = fmaxf(red[qi][0][0], red[qi][1][0]);
    float sum = 0.f;
    #pragma unroll
    for (int j = 0; j < 4; ++j) { s[j] = fexp2((s[j] - m) * L2E); sum += s[j]; }
    *(float4*)&p[qi * 512 + kb2] = *(float4*)s;        // zeros beyond vlen
    #pragma unroll
    for (int off = 32; off; off >>= 1) sum += __shfl_xor(sum, off, 64);
    if (lane == 0) red[qi][half][1] = sum;
    __syncthreads();
  }

  // ---- phase 3: PV, vlen-chunked: all 8 waves split [0, vlen). lane = v.
  {
    const int chunk = ((vlen + 31) >> 5) << 2;   // ceil(vlen/8) -> mult of 4
    const int kb = wave * chunk;
    const float* vb = values + ((size_t)b * K + kb) * V + lane;
    float c0 = 0.f, c1 = 0.f, c2 = 0.f, c3 = 0.f;
    #pragma unroll 4
    for (int k4 = 0; k4 < chunk; k4 += 4) {
      const float4 p0 = *(const float4*)&p[0 * 512 + kb + k4];  // uniform bcast
      const float4 p1 = *(const float4*)&p[1 * 512 + kb + k4];
      const float4 p2 = *(const float4*)&p[2 * 512 + kb + k4];
      const float4 p3 = *(const float4*)&p[3 * 512 + kb + k4];
      const float v0 = vb[(size_t)(k4 + 0) * V];
      const float v1 = vb[(size_t)(k4 + 1) * V];
      const float v2 = vb[(size_t)(k4 + 2) * V];
      const float v3 = vb[(size_t)(k4 + 3) * V];
      c0 = fmaf(p0.x,v0, fmaf(p0.y,v1, fmaf(p0.z,v2, fmaf(p0.w,v3, c0))));
      c1 = fmaf(p1.x,v0, fmaf(p1.y,v1, fmaf(p1.z,v2, fmaf(p1.w,v3, c1))));
      c2 = fmaf(p2.x,v0, fmaf(p2.y,v1, fmaf(p2.z,v2, fmaf(p2.w,v3, c2))));
      c3 = fmaf(p3.x,v0, fmaf(p3.y,v1, fmaf(p3.z,v2, fmaf(p3.w,v3, c3))));
    }
    part[(wave*4+0)*64+lane] = c0; part[(wave*4+1)*64+lane] = c1;
    part[(wave*4+2)*64+lane] = c2; part[(wave*4+3)*64+lane] = c3;
  }
  __syncthreads();

  // ---- phase 4: cross-wave reduce + normalize + write (waves 0..3)
  if (wave < 4) {
    const float inv = frcp(red[wave][0][1] + red[wave][1][1]);
    float o = 0.f;
    #pragma unroll
    for (int w = 0; w < 8; ++w) o += part[(w*4+wave)*64 + lane];
    out[((size_t)b * Q + qg * 4 + wave) * V + lane] = o * inv;
  }
}

extern "C" void kernel_launch(void* const* d_in, const int* in_sizes, int n_in,
                              void* d_out, int out_size, void* d_ws, size_t ws_size,
                              hipStream_t stream) {
  const float* queries = (const float*)d_in[0];
  const float* keys    = (const float*)d_in[1];
  const float* values  = (const float*)d_in[2];
  const int*   vlens   = (const int*)d_in[3];
  const float* Wq      = (const float*)d_in[4];
  const float* Wk      = (const float*)d_in[5];
  const float* wv      = (const float*)d_in[6];
  float* out = (float*)d_out;

  float*    qAR2 = (float*)d_ws;                           // B*16*512 floats (1MB)
  unsigned* Ekp  = (unsigned*)(qAR2 + (size_t)B*16*512);   // B*32*512 dwords (2MB)

  proj_kernel<<<1152, 64, 0, stream>>>(queries, keys, Wq, Wk, wv, vlens, qAR2, Ekp);
  attn_kernel<<<512, 512, 0, stream>>>(qAR2, Ekp, values, vlens, out);
}